// Round 6
// baseline (1914.148 us; speedup 1.0000x reference)
//
#include <hip/hip_runtime.h>
#include <math.h>

// ---------------------------------------------------------------------------
// MuellerMatrixPyramid, fp32, MI355X.
//   conv0 (48->48, 512^2) -> y0 ; mm0 -> m0 ; oconv0 -> out[:,0:17]
//   pool -> x1 ; conv1 -> y1 ; mm1 -> m1 ; bicubic up -> u ; oconv1 -> out[:,17:34]
//
// Conv: software-pipelined, double-buffered LDS tiles, TWO channels per stage,
// ONE barrier per stage (24 stages for CIN=48 vs 47 barriers in R2):
//   gload(c+2) -> compute(c) -> write(c+2), gload(c+3) -> compute(c+1)
//   -> write(c+3) -> barrier.
//
// R6 (post-mortem of R5's 4x regression):
//  - R5's [&]-capture lambdas made hipcc keep acc[8][8] in a scratch frame
//    (WRITE_SIZE 98MB->3.4GB, FETCH 233MB->2.2GB, VALUBusy 13%): the classic
//    can't-SROA-captured-array trap. R6 is the SAME schedule with ZERO
//    lambdas -- all staging/compute written inline (compute duplicated for
//    channel A/B). Tripwire: WRITE_SIZE >> 98MB => scratch returned.
//  - s_load weights in the hot loop are POISON (R3/R4): SMEM shares lgkmcnt
//    with DS and returns out-of-order -> full lgkmcnt(0) drains per o-iter.
//    Weights stay in LDS (wlds); same-address reads are bank-broadcast.
//  - SQ_LDS_BANK_CONFLICT ~2.4e7 is intrinsic wave64-b128 service. Ignore.
//  - g stays in blockIdx.z (same-tile groups at z-stride => same XCD L2).
//  - FMA order per output pixel (c asc, kr, kc) bitwise identical to R2.
// ---------------------------------------------------------------------------

__device__ __forceinline__ float leakyf(float t) { return t >= 0.0f ? t : 0.01f * t; }

// 256 threads = XG x-groups * TH rows; each thread PX px * OCPT out-channels.
// grid.z = B * NG.
template<int CIN, int OCPT, int PX, int TW>
__global__ __launch_bounds__(256, 2)
void conv3x3_leaky(const float* __restrict__ in, const float* __restrict__ wgt,
                   const float* __restrict__ bias, float* __restrict__ out,
                   int H, int W, int COUT, int NG,
                   int in_bstride, int out_bstride, int out_coff)
{
    constexpr int XG     = TW / PX;
    constexpr int TH     = 256 / XG;
    constexpr int COLS   = TW + 2;
    constexpr int ROWS   = TH + 2;
    constexpr int STRIDE = (COLS + 3) & ~3;   // 16B-aligned rows
    constexpr int TSZ    = ROWS * STRIDE;
    constexpr int ELEMS  = ROWS * COLS;
    constexpr int K      = (ELEMS + 255) / 256;
    constexpr int NV     = PX + 2;
    constexpr int S      = (CIN + 1) / 2;     // channel-pair stages

    __shared__ float tile[4 * TSZ];           // 2 buffers x 2 channels
    __shared__ float wlds[CIN * OCPT * 12];   // all weights, staged once

    const int tid   = threadIdx.x;
    const int tx    = tid & (XG - 1);
    const int ty    = tid / XG;
    const int g     = blockIdx.z % NG;
    const int b     = blockIdx.z / NG;
    const int obase = g * OCPT;
    const int row0  = blockIdx.y * TH;
    const int col0  = blockIdx.x * TW;
    const int HW    = H * W;

    // stage ALL weights once: wlds[c][o][k], k padded to 12
    for (int idx = tid; idx < CIN * OCPT * 9; idx += 256) {
        int c  = idx / (OCPT * 9);
        int r2 = idx - c * (OCPT * 9);
        int o  = r2 / 9;
        int k2 = r2 - o * 9;
        int og = obase + o;
        wlds[(c * OCPT + o) * 12 + k2] = (og < COUT) ? wgt[(og * CIN + c) * 9 + k2] : 0.0f;
    }

    // loop-invariant staging offsets (K regs each)
    int goff[K], loff[K];
#pragma unroll
    for (int k = 0; k < K; ++k) {
        int idx = tid + k * 256;
        if (idx < ELEMS) {
            int r  = idx / COLS;
            int cc = idx - r * COLS;
            int gr = row0 - 1 + r;
            int gc = col0 - 1 + cc;
            bool v = (gr >= 0 && gr < H && gc >= 0 && gc < W);
            goff[k] = v ? (gr * W + gc) : -1;
            loff[k] = r * STRIDE + cc;
        } else {
            goff[k] = -1;
            loff[k] = -1;
        }
    }

    const float* inb = in + b * in_bstride;
    float sreg[K];

    // prologue: stage channels 0,1 into buffer 0 (plain inline, no lambdas)
    {
        const float* ic = inb;   // c = 0
#pragma unroll
        for (int k = 0; k < K; ++k) {
            float v = 0.0f;
            if (goff[k] >= 0) v = ic[goff[k]];
            sreg[k] = v;
        }
#pragma unroll
        for (int k = 0; k < K; ++k)
            if (loff[k] >= 0) tile[loff[k]] = sreg[k];
    }
    if (CIN > 1) {
        const float* ic = inb + HW;   // c = 1
#pragma unroll
        for (int k = 0; k < K; ++k) {
            float v = 0.0f;
            if (goff[k] >= 0) v = ic[goff[k]];
            sreg[k] = v;
        }
#pragma unroll
        for (int k = 0; k < K; ++k)
            if (loff[k] >= 0) tile[TSZ + loff[k]] = sreg[k];
    }
    __syncthreads();

    float acc[OCPT][PX];
#pragma unroll
    for (int o = 0; o < OCPT; ++o)
#pragma unroll
        for (int p = 0; p < PX; ++p) acc[o][p] = 0.0f;

    for (int s = 0; s < S; ++s) {
        const float* rb = &tile[(s & 1) * 2 * TSZ];
        float*       wb = &tile[((s + 1) & 1) * 2 * TSZ];
        const int cA = 2 * s, cB = 2 * s + 1;
        const int nA = cA + 2, nB = cB + 2;

        // issue loads for channel nA (latency hides under compute cA)
        if (nA < CIN) {
            const float* ic = inb + (size_t)nA * HW;
#pragma unroll
            for (int k = 0; k < K; ++k) {
                float v = 0.0f;
                if (goff[k] >= 0) v = ic[goff[k]];
                sreg[k] = v;
            }
        }

        // ---- compute channel cA from rb ----
        {
            float v[3][NV];
#pragma unroll
            for (int rr = 0; rr < 3; ++rr) {
                const float* tp = rb + (ty + rr) * STRIDE + tx * PX;
                float4 a0 = *(const float4*)tp;
                v[rr][0] = a0.x; v[rr][1] = a0.y; v[rr][2] = a0.z; v[rr][3] = a0.w;
                if constexpr (PX == 8) {
                    float4 a1 = *(const float4*)(tp + 4);
                    float2 a2 = *(const float2*)(tp + 8);
                    v[rr][4] = a1.x; v[rr][5] = a1.y; v[rr][6] = a1.z; v[rr][7] = a1.w;
                    v[rr][8] = a2.x; v[rr][9] = a2.y;
                } else {
                    float2 a1 = *(const float2*)(tp + 4);
                    v[rr][4] = a1.x; v[rr][5] = a1.y;
                }
            }
#pragma unroll
            for (int o = 0; o < OCPT; ++o) {
                const float* wp = &wlds[(cA * OCPT + o) * 12];
                float4 w0 = *(const float4*)wp;
                float4 w1 = *(const float4*)(wp + 4);
                float w8 = wp[8];
                float wk[9] = {w0.x, w0.y, w0.z, w0.w, w1.x, w1.y, w1.z, w1.w, w8};
#pragma unroll
                for (int px = 0; px < PX; ++px) {
                    float t = acc[o][px];
#pragma unroll
                    for (int kr = 0; kr < 3; ++kr)
#pragma unroll
                        for (int kc = 0; kc < 3; ++kc)
                            t = fmaf(wk[kr * 3 + kc], v[kr][px + kc], t);
                    acc[o][px] = t;
                }
            }
        }

        // write nA into other buffer; issue loads for nB
        if (nA < CIN) {
#pragma unroll
            for (int k = 0; k < K; ++k)
                if (loff[k] >= 0) wb[loff[k]] = sreg[k];
            if (nB < CIN) {
                const float* ic = inb + (size_t)nB * HW;
#pragma unroll
                for (int k = 0; k < K; ++k) {
                    float v = 0.0f;
                    if (goff[k] >= 0) v = ic[goff[k]];
                    sreg[k] = v;
                }
            }
        }

        // ---- compute channel cB from rb+TSZ ----
        if (cB < CIN) {
            const float* rb2 = rb + TSZ;
            float v[3][NV];
#pragma unroll
            for (int rr = 0; rr < 3; ++rr) {
                const float* tp = rb2 + (ty + rr) * STRIDE + tx * PX;
                float4 a0 = *(const float4*)tp;
                v[rr][0] = a0.x; v[rr][1] = a0.y; v[rr][2] = a0.z; v[rr][3] = a0.w;
                if constexpr (PX == 8) {
                    float4 a1 = *(const float4*)(tp + 4);
                    float2 a2 = *(const float2*)(tp + 8);
                    v[rr][4] = a1.x; v[rr][5] = a1.y; v[rr][6] = a1.z; v[rr][7] = a1.w;
                    v[rr][8] = a2.x; v[rr][9] = a2.y;
                } else {
                    float2 a1 = *(const float2*)(tp + 4);
                    v[rr][4] = a1.x; v[rr][5] = a1.y;
                }
            }
#pragma unroll
            for (int o = 0; o < OCPT; ++o) {
                const float* wp = &wlds[(cB * OCPT + o) * 12];
                float4 w0 = *(const float4*)wp;
                float4 w1 = *(const float4*)(wp + 4);
                float w8 = wp[8];
                float wk[9] = {w0.x, w0.y, w0.z, w0.w, w1.x, w1.y, w1.z, w1.w, w8};
#pragma unroll
                for (int px = 0; px < PX; ++px) {
                    float t = acc[o][px];
#pragma unroll
                    for (int kr = 0; kr < 3; ++kr)
#pragma unroll
                        for (int kc = 0; kc < 3; ++kc)
                            t = fmaf(wk[kr * 3 + kc], v[kr][px + kc], t);
                    acc[o][px] = t;
                }
            }
        }

        // write nB, then ONE barrier per 2-channel stage
        if (nA < CIN) {
            if (nB < CIN) {
                float* wb2 = wb + TSZ;
#pragma unroll
                for (int k = 0; k < K; ++k)
                    if (loff[k] >= 0) wb2[loff[k]] = sreg[k];
            }
            __syncthreads();                 // uniform (s, CIN) -> legal
        }
    }

    const int orow = row0 + ty;
    float* outb = out + b * out_bstride;
#pragma unroll
    for (int o = 0; o < OCPT; ++o) {
        int og = obase + o;
        if (og < COUT) {
            float bv = bias[og];            // epilogue-only scalar load: harmless
            float r[PX];
#pragma unroll
            for (int p = 0; p < PX; ++p) { float t = acc[o][p] + bv; r[p] = leakyf(t); }
            float* op = outb + ((out_coff + og) * H + orow) * W + col0 + tx * PX;
#pragma unroll
            for (int q = 0; q < PX / 4; ++q)
                *(float4*)(op + 4 * q) = make_float4(r[4*q], r[4*q+1], r[4*q+2], r[4*q+3]);
        }
    }
}

// ---------------- 4x4 inverse (double, adjugate) ---------------------------
__device__ __forceinline__ void inv4x4(const double* m, double* invOut)
{
    double inv[16];
    inv[0]  =  m[5]*m[10]*m[15] - m[5]*m[11]*m[14] - m[9]*m[6]*m[15] + m[9]*m[7]*m[14] + m[13]*m[6]*m[11] - m[13]*m[7]*m[10];
    inv[4]  = -m[4]*m[10]*m[15] + m[4]*m[11]*m[14] + m[8]*m[6]*m[15] - m[8]*m[7]*m[14] - m[12]*m[6]*m[11] + m[12]*m[7]*m[10];
    inv[8]  =  m[4]*m[9]*m[15]  - m[4]*m[11]*m[13] - m[8]*m[5]*m[15] + m[8]*m[7]*m[13] + m[12]*m[5]*m[11] - m[12]*m[7]*m[9];
    inv[12] = -m[4]*m[9]*m[14]  + m[4]*m[10]*m[13] + m[8]*m[5]*m[14] - m[8]*m[6]*m[13] - m[12]*m[5]*m[10] + m[12]*m[6]*m[9];
    inv[1]  = -m[1]*m[10]*m[15] + m[1]*m[11]*m[14] + m[9]*m[2]*m[15] - m[9]*m[3]*m[14] - m[13]*m[2]*m[11] + m[13]*m[3]*m[10];
    inv[5]  =  m[0]*m[10]*m[15] - m[0]*m[11]*m[14] - m[8]*m[2]*m[15] + m[8]*m[3]*m[14] + m[12]*m[2]*m[11] - m[12]*m[3]*m[10];
    inv[9]  = -m[0]*m[9]*m[15]  + m[0]*m[11]*m[13] + m[8]*m[1]*m[15] - m[8]*m[3]*m[13] - m[12]*m[1]*m[11] + m[12]*m[3]*m[9];
    inv[13] =  m[0]*m[9]*m[14]  - m[0]*m[10]*m[13] - m[8]*m[1]*m[14] + m[8]*m[2]*m[13] + m[12]*m[1]*m[10] - m[12]*m[2]*m[9];
    inv[2]  =  m[1]*m[6]*m[15]  - m[1]*m[7]*m[14]  - m[5]*m[2]*m[15] + m[5]*m[3]*m[14] + m[13]*m[2]*m[7]  - m[13]*m[3]*m[6];
    inv[6]  = -m[0]*m[6]*m[15]  + m[0]*m[7]*m[14]  + m[4]*m[2]*m[15] - m[4]*m[3]*m[14] - m[12]*m[2]*m[7]  + m[12]*m[3]*m[6];
    inv[10] =  m[0]*m[5]*m[15]  - m[0]*m[7]*m[13]  - m[4]*m[1]*m[15] + m[4]*m[3]*m[13] + m[12]*m[1]*m[7]  - m[12]*m[3]*m[5];
    inv[14] = -m[0]*m[5]*m[14]  + m[0]*m[6]*m[13]  + m[4]*m[1]*m[14] - m[4]*m[2]*m[13] - m[12]*m[1]*m[6]  + m[12]*m[2]*m[5];
    inv[3]  = -m[1]*m[6]*m[11]  + m[1]*m[7]*m[10]  + m[5]*m[2]*m[11] - m[5]*m[3]*m[10] - m[9]*m[2]*m[7]   + m[9]*m[3]*m[6];
    inv[7]  =  m[0]*m[6]*m[11]  - m[0]*m[7]*m[10]  - m[4]*m[2]*m[11] + m[4]*m[3]*m[10] + m[8]*m[2]*m[7]   - m[8]*m[3]*m[6];
    inv[11] = -m[0]*m[5]*m[11]  + m[0]*m[7]*m[9]   + m[4]*m[1]*m[11] - m[4]*m[3]*m[9]  - m[8]*m[1]*m[7]   + m[8]*m[3]*m[5];
    inv[15] =  m[0]*m[5]*m[10]  - m[0]*m[6]*m[9]   - m[4]*m[1]*m[10] + m[4]*m[2]*m[9]  + m[8]*m[1]*m[6]   - m[8]*m[2]*m[5];
    double det = m[0]*inv[0] + m[1]*inv[4] + m[2]*inv[8] + m[3]*inv[12];
    det = 1.0 / det;
#pragma unroll
    for (int i = 0; i < 16; ++i) invOut[i] = inv[i] * det;
}

__device__ __forceinline__ void matmul4(const double* A, const double* B, double* C)
{
#pragma unroll
    for (int r = 0; r < 4; ++r)
#pragma unroll
        for (int c = 0; c < 4; ++c) {
            double s = 0.0;
#pragma unroll
            for (int k = 0; k < 4; ++k) s += A[r * 4 + k] * B[k * 4 + c];
            C[r * 4 + c] = s;
        }
}

// ---------------- mm_features: (b,48,h,w) -> (b,17,h,w) --------------------
__global__ __launch_bounds__(256)
void mm_features_kernel(const float* __restrict__ y, float* __restrict__ m, int HW, int n)
{
    int p = blockIdx.x * 256 + threadIdx.x;
    if (p >= n) return;
    int b  = p / HW;
    int sp = p - b * HW;
    const float* base = y + (size_t)b * 48 * HW + sp;

    double A[16];
#pragma unroll
    for (int i = 0; i < 16; ++i) {
        double e = (i == 0 || i == 5 || i == 10 || i == 15) ? 1e-4 : 0.0;
        A[i] = (double)base[(16 + i) * HW] + e;
    }
    double iA[16];
    inv4x4(A, iA);                     // A dead

    double F[16];
    double s = 0.0;
#pragma unroll
    for (int i = 0; i < 16; ++i) { F[i] = (double)base[i * HW]; }
#pragma unroll
    for (int i = 0; i < 16; ++i) s += F[i];
    s *= (1.0 / 16.0);

    double T[16];
    matmul4(iA, F, T);                 // iA, F dead

    double Wm[16];
#pragma unroll
    for (int i = 0; i < 16; ++i) {
        double e = (i == 0 || i == 5 || i == 10 || i == 15) ? 1e-4 : 0.0;
        Wm[i] = (double)base[(32 + i) * HW] + e;
    }
    double iW[16];
    inv4x4(Wm, iW);                    // Wm dead

    double M[16];
    matmul4(T, iW, M);

    float* ob = m + (size_t)b * 17 * HW + sp;
    ob[0] = (float)s;
#pragma unroll
    for (int i = 0; i < 16; ++i) ob[(1 + i) * HW] = (float)M[i];
}

// ---------------- 4x4 maxpool: (2,48,512,512) -> (2,48,128,128) ------------
__global__ __launch_bounds__(256)
void maxpool4_kernel(const float* __restrict__ in, float* __restrict__ out, int n)
{
    int idx = blockIdx.x * 256 + threadIdx.x;
    if (idx >= n) return;
    int ow = idx & 127;
    int oh = (idx >> 7) & 127;
    int ct = idx >> 14;                 // b*48 + c
    const float* p = in + ct * 262144 + (oh * 4) * 512 + ow * 4;
    float mx = -3.4e38f;
#pragma unroll
    for (int r = 0; r < 4; ++r) {
        float4 v = *(const float4*)(p + r * 512);
        mx = fmaxf(mx, fmaxf(fmaxf(v.x, v.y), fmaxf(v.z, v.w)));
    }
    out[idx] = mx;
}

// ---------------- bicubic x4 upsample 128->512, align_corners, a=-0.75 -----
__device__ __forceinline__ double cubw(double t)
{
    const double a = -0.75;
    t = fabs(t);
    if (t <= 1.0) return ((a + 2.0) * t - (a + 3.0)) * t * t + 1.0;
    if (t < 2.0)  return (((t - 5.0) * t + 8.0) * t - 4.0) * a;
    return 0.0;
}

__global__ __launch_bounds__(256)
void bicubic_up4_kernel(const float* __restrict__ src, float* __restrict__ dst, int n)
{
    int idx = blockIdx.x * 256 + threadIdx.x;
    if (idx >= n) return;
    int P  = idx & 511;
    int O  = (idx >> 9) & 511;
    int bc = idx >> 18;                 // b*17 + c
    const double scale = 127.0 / 511.0;
    double sh = O * scale, sw = P * scale;
    int i0 = (int)floor(sh), j0 = (int)floor(sw);
    double wh[4], ww[4];
#pragma unroll
    for (int k = 0; k < 4; ++k) {
        wh[k] = cubw(sh - (double)(i0 + k - 1));
        ww[k] = cubw(sw - (double)(j0 + k - 1));
    }
    const float* sp = src + bc * 16384;
    double acc = 0.0;
#pragma unroll
    for (int ki = 0; ki < 4; ++ki) {
        int ih = min(max(i0 - 1 + ki, 0), 127);
        double rs = 0.0;
#pragma unroll
        for (int kj = 0; kj < 4; ++kj) {
            int iw = min(max(j0 - 1 + kj, 0), 127);
            rs += ww[kj] * (double)sp[ih * 128 + iw];
        }
        acc += wh[ki] * rs;
    }
    dst[idx] = (float)acc;
}

// ---------------------------------------------------------------------------
extern "C" void kernel_launch(void* const* d_in, const int* in_sizes, int n_in,
                              void* d_out, int out_size, void* d_ws, size_t ws_size,
                              hipStream_t stream)
{
    const float* x   = (const float*)d_in[0];
    const float* iW0 = (const float*)d_in[1];
    const float* iB0 = (const float*)d_in[2];
    const float* iW1 = (const float*)d_in[3];
    const float* iB1 = (const float*)d_in[4];
    const float* oW0 = (const float*)d_in[5];
    const float* oB0 = (const float*)d_in[6];
    const float* oW1 = (const float*)d_in[7];
    const float* oB1 = (const float*)d_in[8];
    float* out = (float*)d_out;
    float* ws  = (float*)d_ws;

    // workspace layout (floats)
    float* y0 = ws;                     //  2*48*512*512 = 25165824
    float* m0 = ws + 25165824;          //  2*17*512*512 =  8912896
    float* x1 = ws + 34078720;          //  2*48*128*128 =  1572864
    float* y1 = ws + 35651584;          //  1572864
    float* m1 = ws + 37224448;          //  2*17*128*128 =   557056
    float* u  = ws;                     //  reuse y0 region (y0 dead by then)

    // level 0
    conv3x3_leaky<48, 8, 8, 64><<<dim3(8, 16, 12), 256, 0, stream>>>(
        x, iW0, iB0, y0, 512, 512, 48, 6, 48 * 512 * 512, 48 * 512 * 512, 0);
    mm_features_kernel<<<(2 * 512 * 512) / 256, 256, 0, stream>>>(y0, m0, 512 * 512, 2 * 512 * 512);
    conv3x3_leaky<17, 9, 8, 64><<<dim3(8, 16, 4), 256, 0, stream>>>(
        m0, oW0, oB0, out, 512, 512, 17, 2, 17 * 512 * 512, 34 * 512 * 512, 0);
    maxpool4_kernel<<<(2 * 48 * 128 * 128) / 256, 256, 0, stream>>>(y0, x1, 2 * 48 * 128 * 128);

    // level 1 (128^2: 32x32 tiles, OCPT=4 -> 384 blocks)
    conv3x3_leaky<48, 4, 4, 32><<<dim3(4, 4, 24), 256, 0, stream>>>(
        x1, iW1, iB1, y1, 128, 128, 48, 12, 48 * 128 * 128, 48 * 128 * 128, 0);
    mm_features_kernel<<<(2 * 128 * 128) / 256, 256, 0, stream>>>(y1, m1, 128 * 128, 2 * 128 * 128);
    bicubic_up4_kernel<<<(2 * 17 * 512 * 512) / 256, 256, 0, stream>>>(m1, u, 2 * 17 * 512 * 512);
    conv3x3_leaky<17, 9, 8, 64><<<dim3(8, 16, 4), 256, 0, stream>>>(
        u, oW1, oB1, out, 512, 512, 17, 2, 17 * 512 * 512, 34 * 512 * 512, 17);
}

// Round 7
// 714.169 us; speedup vs baseline: 2.6802x; 2.6802x over previous
//
#include <hip/hip_runtime.h>
#include <math.h>

// ---------------------------------------------------------------------------
// MuellerMatrixPyramid, fp32, MI355X.
//   conv0 (48->48, 512^2) -> y0 (+fused 4x4 maxpool -> x1)
//   mm0   (y0 -> m0, 17ch)
//   oconv0(m0 -> out[:,0:17])
//   conv1 (48->48, 128^2) -> y1
//   mm1   (y1 -> m1)
//   up    (m1 -> u, bicubic a=-0.75 align_corners, 128->512)
//   oconv1(u -> out[:,17:34])
//
// Conv: R2-proven structure: software-pipelined, double-buffered LDS, ONE
// barrier per channel: load(c+1) regs -> compute(c) from LDS -> ds_write(c+1)
// -> barrier. VGPR 120, no spill.
//
// HARD-WON RULES (R3-R6 post-mortems):
//  - 128-VGPR CLIFF: hipcc refuses to allocate past 128 (4-waves/SIMD
//    target); excess live set SPILLS acc to scratch (R5/R6: VGPR=128,
//    5.8 GB/dispatch scratch traffic, 4x slowdown). Identical with and
//    without lambdas. Any schedule change adding >~8 live regs dies.
//    => 2-channels-per-stage pipelining is a DEAD END at this tile size.
//  - s_load weights in the hot loop are POISON: SMEM shares lgkmcnt with DS,
//    returns out-of-order -> full lgkmcnt(0) drains serialize the tile-read
//    pipeline (R3/R4: +50us). Weights stay in LDS; same-address wave reads
//    are bank-broadcast (cheap).
//  - XCD remap of g to fastest blockIdx.x is WRONG: consecutive blocks
//    round-robin over 8 XCDs -> same-tile groups land on 6 different L2s
//    (R3: FETCH 233->390MB). g stays in blockIdx.z.
//  - SQ_LDS_BANK_CONFLICT ~2.4e7 is intrinsic wave64-b128 service. Ignore.
//
// R7: conv back to R2 verbatim + maxpool fused into conv0 epilogue
// (template<DO_POOL>): stages post-activation channel-pairs through the dead
// tile LDS (16KB <= 18.5KB), writes x1 directly. Kills the standalone pool
// kernel (100.6MB re-read of y0). Epilogue-only; hot loop untouched.
// ---------------------------------------------------------------------------

__device__ __forceinline__ float leakyf(float t) { return t >= 0.0f ? t : 0.01f * t; }

// 256 threads = XG x-groups * TH rows; each thread PX px * OCPT out-channels.
// grid.z = B * NG.
template<int CIN, int OCPT, int PX, int TW, bool DO_POOL>
__global__ __launch_bounds__(256, 2)
void conv3x3_leaky(const float* __restrict__ in, const float* __restrict__ wgt,
                   const float* __restrict__ bias, float* __restrict__ out,
                   float* __restrict__ pool_out,
                   int H, int W, int COUT, int NG,
                   int in_bstride, int out_bstride, int out_coff)
{
    constexpr int XG     = TW / PX;
    constexpr int TH     = 256 / XG;
    constexpr int COLS   = TW + 2;
    constexpr int ROWS   = TH + 2;
    constexpr int STRIDE = (COLS + 3) & ~3;   // 16B-aligned rows
    constexpr int TSZ    = ROWS * STRIDE;
    constexpr int ELEMS  = ROWS * COLS;
    constexpr int K      = (ELEMS + 255) / 256;
    constexpr int NV     = PX + 2;

    __shared__ float tile[2 * TSZ];           // double buffer
    __shared__ float wlds[CIN * OCPT * 12];   // all weights, staged once
    __shared__ float blds[OCPT];

    const int tid   = threadIdx.x;
    const int tx    = tid & (XG - 1);
    const int ty    = tid / XG;
    const int g     = blockIdx.z % NG;
    const int b     = blockIdx.z / NG;
    const int obase = g * OCPT;
    const int row0  = blockIdx.y * TH;
    const int col0  = blockIdx.x * TW;
    const int HW    = H * W;

    // stage ALL weights once: wlds[c][o][k], k padded to 12
    for (int idx = tid; idx < CIN * OCPT * 9; idx += 256) {
        int c  = idx / (OCPT * 9);
        int r2 = idx - c * (OCPT * 9);
        int o  = r2 / 9;
        int k2 = r2 - o * 9;
        int og = obase + o;
        wlds[(c * OCPT + o) * 12 + k2] = (og < COUT) ? wgt[(og * CIN + c) * 9 + k2] : 0.0f;
    }
    if (tid < OCPT) {
        int og = obase + tid;
        blds[tid] = (og < COUT) ? bias[og] : 0.0f;
    }

    // loop-invariant staging offsets (K regs each)
    int goff[K], loff[K];
#pragma unroll
    for (int k = 0; k < K; ++k) {
        int idx = tid + k * 256;
        if (idx < ELEMS) {
            int r  = idx / COLS;
            int cc = idx - r * COLS;
            int gr = row0 - 1 + r;
            int gc = col0 - 1 + cc;
            bool v = (gr >= 0 && gr < H && gc >= 0 && gc < W);
            goff[k] = v ? (gr * W + gc) : -1;
            loff[k] = r * STRIDE + cc;
        } else {
            goff[k] = -1;
            loff[k] = -1;
        }
    }

    const float* inb = in + b * in_bstride;

    // prologue: stage channel 0 into buffer 0
    float sreg[K];
    {
        const float* ic = inb;   // c = 0
#pragma unroll
        for (int k = 0; k < K; ++k) {
            float v = 0.0f;
            if (goff[k] >= 0) v = ic[goff[k]];
            sreg[k] = v;
        }
#pragma unroll
        for (int k = 0; k < K; ++k)
            if (loff[k] >= 0) tile[loff[k]] = sreg[k];
    }
    __syncthreads();

    float acc[OCPT][PX];
#pragma unroll
    for (int o = 0; o < OCPT; ++o)
#pragma unroll
        for (int p = 0; p < PX; ++p) acc[o][p] = 0.0f;

    for (int c = 0; c < CIN; ++c) {
        // issue next channel's loads (latency overlaps this channel's FMAs)
        if (c + 1 < CIN) {
            const float* ic = inb + (c + 1) * HW;
#pragma unroll
            for (int k = 0; k < K; ++k) {
                float v = 0.0f;
                if (goff[k] >= 0) v = ic[goff[k]];
                sreg[k] = v;
            }
        }

        // compute channel c from buffer (c&1)
        {
            const float* tb = &tile[(c & 1) * TSZ];
            float v[3][NV];
#pragma unroll
            for (int rr = 0; rr < 3; ++rr) {
                const float* tp = tb + (ty + rr) * STRIDE + tx * PX;
                float4 a0 = *(const float4*)tp;
                v[rr][0] = a0.x; v[rr][1] = a0.y; v[rr][2] = a0.z; v[rr][3] = a0.w;
                if constexpr (PX == 8) {
                    float4 a1 = *(const float4*)(tp + 4);
                    float2 a2 = *(const float2*)(tp + 8);
                    v[rr][4] = a1.x; v[rr][5] = a1.y; v[rr][6] = a1.z; v[rr][7] = a1.w;
                    v[rr][8] = a2.x; v[rr][9] = a2.y;
                } else {
                    float2 a1 = *(const float2*)(tp + 4);
                    v[rr][4] = a1.x; v[rr][5] = a1.y;
                }
            }
#pragma unroll
            for (int o = 0; o < OCPT; ++o) {
                const float* wp = &wlds[(c * OCPT + o) * 12];
                float4 w0 = *(const float4*)wp;
                float4 w1 = *(const float4*)(wp + 4);
                float w8 = wp[8];
                float wk[9] = {w0.x, w0.y, w0.z, w0.w, w1.x, w1.y, w1.z, w1.w, w8};
#pragma unroll
                for (int px = 0; px < PX; ++px) {
                    float s = acc[o][px];
#pragma unroll
                    for (int kr = 0; kr < 3; ++kr)
#pragma unroll
                        for (int kc = 0; kc < 3; ++kc)
                            s = fmaf(wk[kr * 3 + kc], v[kr][px + kc], s);
                    acc[o][px] = s;
                }
            }
        }

        // write next channel's tile into the other buffer, then barrier
        if (c + 1 < CIN) {
            float* tb = &tile[((c + 1) & 1) * TSZ];
#pragma unroll
            for (int k = 0; k < K; ++k)
                if (loff[k] >= 0) tb[loff[k]] = sreg[k];
            __syncthreads();   // uniform branch (c uniform) -> legal
        }
    }

    const int orow = row0 + ty;
    float* outb = out + b * out_bstride;
#pragma unroll
    for (int o = 0; o < OCPT; ++o) {
        int og = obase + o;
        if (og < COUT) {
            float bv = blds[o];
            float r[PX];
#pragma unroll
            for (int p = 0; p < PX; ++p) { float t = acc[o][p] + bv; r[p] = leakyf(t); }
            float* op = outb + ((out_coff + og) * H + orow) * W + col0 + tx * PX;
#pragma unroll
            for (int q = 0; q < PX / 4; ++q)
                *(float4*)(op + 4 * q) = make_float4(r[4*q], r[4*q+1], r[4*q+2], r[4*q+3]);
        }
    }

    // ---- fused 4x4 maxpool (conv0 only): acc -> LDS (channel pairs) -> x1 ----
    if constexpr (DO_POOL) {
        static_assert(2 * TSZ >= 2 * TH * TW, "pool staging must fit tile LDS");
        static_assert(TH == 32 && TW == 64, "pool mapping assumes 32x64 tile");
        const int pH = H >> 2, pW = W >> 2;
        const int prow0 = row0 >> 2, pcol0 = col0 >> 2;
        float* pbuf = tile;                    // tile is dead after main loop
#pragma unroll
        for (int o2 = 0; o2 < OCPT / 2; ++o2) {
            __syncthreads();                   // prev pbuf reads / last tile reads done
#pragma unroll
            for (int half = 0; half < 2; ++half) {
                int o = o2 * 2 + half;
                float bv = blds[o];
                float* pb = pbuf + half * (TH * TW) + ty * TW + tx * PX;
#pragma unroll
                for (int p = 0; p < PX; ++p) pb[p] = leakyf(acc[o][p] + bv);
            }
            __syncthreads();
            // 256 threads -> 2ch x 8pr x 16pc pooled outputs
            int c2 = tid >> 7;
            int pr = (tid >> 4) & 7;
            int pc = tid & 15;
            const float* pb = pbuf + c2 * (TH * TW) + (pr * 4) * TW + pc * 4;
            float mx = -3.4e38f;
#pragma unroll
            for (int rr = 0; rr < 4; ++rr) {
                float4 v = *(const float4*)(pb + rr * TW);
                mx = fmaxf(mx, fmaxf(fmaxf(v.x, v.y), fmaxf(v.z, v.w)));
            }
            int og = obase + o2 * 2 + c2;
            pool_out[((b * COUT + og) * pH + prow0 + pr) * pW + pcol0 + pc] = mx;
        }
    }
}

// ---------------- 4x4 inverse (double, adjugate) ---------------------------
__device__ __forceinline__ void inv4x4(const double* m, double* invOut)
{
    double inv[16];
    inv[0]  =  m[5]*m[10]*m[15] - m[5]*m[11]*m[14] - m[9]*m[6]*m[15] + m[9]*m[7]*m[14] + m[13]*m[6]*m[11] - m[13]*m[7]*m[10];
    inv[4]  = -m[4]*m[10]*m[15] + m[4]*m[11]*m[14] + m[8]*m[6]*m[15] - m[8]*m[7]*m[14] - m[12]*m[6]*m[11] + m[12]*m[7]*m[10];
    inv[8]  =  m[4]*m[9]*m[15]  - m[4]*m[11]*m[13] - m[8]*m[5]*m[15] + m[8]*m[7]*m[13] + m[12]*m[5]*m[11] - m[12]*m[7]*m[9];
    inv[12] = -m[4]*m[9]*m[14]  + m[4]*m[10]*m[13] + m[8]*m[5]*m[14] - m[8]*m[6]*m[13] - m[12]*m[5]*m[10] + m[12]*m[6]*m[9];
    inv[1]  = -m[1]*m[10]*m[15] + m[1]*m[11]*m[14] + m[9]*m[2]*m[15] - m[9]*m[3]*m[14] - m[13]*m[2]*m[11] + m[13]*m[3]*m[10];
    inv[5]  =  m[0]*m[10]*m[15] - m[0]*m[11]*m[14] - m[8]*m[2]*m[15] + m[8]*m[3]*m[14] + m[12]*m[2]*m[11] - m[12]*m[3]*m[10];
    inv[9]  = -m[0]*m[9]*m[15]  + m[0]*m[11]*m[13] + m[8]*m[1]*m[15] - m[8]*m[3]*m[13] - m[12]*m[1]*m[11] + m[12]*m[3]*m[9];
    inv[13] =  m[0]*m[9]*m[14]  - m[0]*m[10]*m[13] - m[8]*m[1]*m[14] + m[8]*m[2]*m[13] + m[12]*m[1]*m[10] - m[12]*m[2]*m[9];
    inv[2]  =  m[1]*m[6]*m[15]  - m[1]*m[7]*m[14]  - m[5]*m[2]*m[15] + m[5]*m[3]*m[14] + m[13]*m[2]*m[7]  - m[13]*m[3]*m[6];
    inv[6]  = -m[0]*m[6]*m[15]  + m[0]*m[7]*m[14]  + m[4]*m[2]*m[15] - m[4]*m[3]*m[14] - m[12]*m[2]*m[7]  + m[12]*m[3]*m[6];
    inv[10] =  m[0]*m[5]*m[15]  - m[0]*m[7]*m[13]  - m[4]*m[1]*m[15] + m[4]*m[3]*m[13] + m[12]*m[1]*m[7]  - m[12]*m[3]*m[5];
    inv[14] = -m[0]*m[5]*m[14]  + m[0]*m[6]*m[13]  + m[4]*m[1]*m[14] - m[4]*m[2]*m[13] - m[12]*m[1]*m[6]  + m[12]*m[2]*m[5];
    inv[3]  = -m[1]*m[6]*m[11]  + m[1]*m[7]*m[10]  + m[5]*m[2]*m[11] - m[5]*m[3]*m[10] - m[9]*m[2]*m[7]   + m[9]*m[3]*m[6];
    inv[7]  =  m[0]*m[6]*m[11]  - m[0]*m[7]*m[10]  - m[4]*m[2]*m[11] + m[4]*m[3]*m[10] + m[8]*m[2]*m[7]   - m[8]*m[3]*m[6];
    inv[11] = -m[0]*m[5]*m[11]  + m[0]*m[7]*m[9]   + m[4]*m[1]*m[11] - m[4]*m[3]*m[9]  - m[8]*m[1]*m[7]   + m[8]*m[3]*m[5];
    inv[15] =  m[0]*m[5]*m[10]  - m[0]*m[6]*m[9]   - m[4]*m[1]*m[10] + m[4]*m[2]*m[9]  + m[8]*m[1]*m[6]   - m[8]*m[2]*m[5];
    double det = m[0]*inv[0] + m[1]*inv[4] + m[2]*inv[8] + m[3]*inv[12];
    det = 1.0 / det;
#pragma unroll
    for (int i = 0; i < 16; ++i) invOut[i] = inv[i] * det;
}

__device__ __forceinline__ void matmul4(const double* A, const double* B, double* C)
{
#pragma unroll
    for (int r = 0; r < 4; ++r)
#pragma unroll
        for (int c = 0; c < 4; ++c) {
            double s = 0.0;
#pragma unroll
            for (int k = 0; k < 4; ++k) s += A[r * 4 + k] * B[k * 4 + c];
            C[r * 4 + c] = s;
        }
}

// ---------------- mm_features: (b,48,h,w) -> (b,17,h,w) --------------------
__global__ __launch_bounds__(256)
void mm_features_kernel(const float* __restrict__ y, float* __restrict__ m, int HW, int n)
{
    int p = blockIdx.x * 256 + threadIdx.x;
    if (p >= n) return;
    int b  = p / HW;
    int sp = p - b * HW;
    const float* base = y + (size_t)b * 48 * HW + sp;

    double A[16];
#pragma unroll
    for (int i = 0; i < 16; ++i) {
        double e = (i == 0 || i == 5 || i == 10 || i == 15) ? 1e-4 : 0.0;
        A[i] = (double)base[(16 + i) * HW] + e;
    }
    double iA[16];
    inv4x4(A, iA);                     // A dead

    double F[16];
    double s = 0.0;
#pragma unroll
    for (int i = 0; i < 16; ++i) { F[i] = (double)base[i * HW]; }
#pragma unroll
    for (int i = 0; i < 16; ++i) s += F[i];
    s *= (1.0 / 16.0);

    double T[16];
    matmul4(iA, F, T);                 // iA, F dead

    double Wm[16];
#pragma unroll
    for (int i = 0; i < 16; ++i) {
        double e = (i == 0 || i == 5 || i == 10 || i == 15) ? 1e-4 : 0.0;
        Wm[i] = (double)base[(32 + i) * HW] + e;
    }
    double iW[16];
    inv4x4(Wm, iW);                    // Wm dead

    double M[16];
    matmul4(T, iW, M);

    float* ob = m + (size_t)b * 17 * HW + sp;
    ob[0] = (float)s;
#pragma unroll
    for (int i = 0; i < 16; ++i) ob[(1 + i) * HW] = (float)M[i];
}

// ---------------- bicubic x4 upsample 128->512, align_corners, a=-0.75 -----
__device__ __forceinline__ double cubw(double t)
{
    const double a = -0.75;
    t = fabs(t);
    if (t <= 1.0) return ((a + 2.0) * t - (a + 3.0)) * t * t + 1.0;
    if (t < 2.0)  return (((t - 5.0) * t + 8.0) * t - 4.0) * a;
    return 0.0;
}

__global__ __launch_bounds__(256)
void bicubic_up4_kernel(const float* __restrict__ src, float* __restrict__ dst, int n)
{
    int idx = blockIdx.x * 256 + threadIdx.x;
    if (idx >= n) return;
    int P  = idx & 511;
    int O  = (idx >> 9) & 511;
    int bc = idx >> 18;                 // b*17 + c
    const double scale = 127.0 / 511.0;
    double sh = O * scale, sw = P * scale;
    int i0 = (int)floor(sh), j0 = (int)floor(sw);
    double wh[4], ww[4];
#pragma unroll
    for (int k = 0; k < 4; ++k) {
        wh[k] = cubw(sh - (double)(i0 + k - 1));
        ww[k] = cubw(sw - (double)(j0 + k - 1));
    }
    const float* sp = src + bc * 16384;
    double acc = 0.0;
#pragma unroll
    for (int ki = 0; ki < 4; ++ki) {
        int ih = min(max(i0 - 1 + ki, 0), 127);
        double rs = 0.0;
#pragma unroll
        for (int kj = 0; kj < 4; ++kj) {
            int iw = min(max(j0 - 1 + kj, 0), 127);
            rs += ww[kj] * (double)sp[ih * 128 + iw];
        }
        acc += wh[ki] * rs;
    }
    dst[idx] = (float)acc;
}

// ---------------------------------------------------------------------------
extern "C" void kernel_launch(void* const* d_in, const int* in_sizes, int n_in,
                              void* d_out, int out_size, void* d_ws, size_t ws_size,
                              hipStream_t stream)
{
    const float* x   = (const float*)d_in[0];
    const float* iW0 = (const float*)d_in[1];
    const float* iB0 = (const float*)d_in[2];
    const float* iW1 = (const float*)d_in[3];
    const float* iB1 = (const float*)d_in[4];
    const float* oW0 = (const float*)d_in[5];
    const float* oB0 = (const float*)d_in[6];
    const float* oW1 = (const float*)d_in[7];
    const float* oB1 = (const float*)d_in[8];
    float* out = (float*)d_out;
    float* ws  = (float*)d_ws;

    // workspace layout (floats)
    float* y0 = ws;                     //  2*48*512*512 = 25165824
    float* m0 = ws + 25165824;          //  2*17*512*512 =  8912896
    float* x1 = ws + 34078720;          //  2*48*128*128 =  1572864
    float* y1 = ws + 35651584;          //  1572864
    float* m1 = ws + 37224448;          //  2*17*128*128 =   557056
    float* u  = ws;                     //  reuse y0 region (y0 dead by then)

    // level 0 (maxpool fused into conv0 epilogue -> x1)
    conv3x3_leaky<48, 8, 8, 64, true><<<dim3(8, 16, 12), 256, 0, stream>>>(
        x, iW0, iB0, y0, x1, 512, 512, 48, 6, 48 * 512 * 512, 48 * 512 * 512, 0);
    mm_features_kernel<<<(2 * 512 * 512) / 256, 256, 0, stream>>>(y0, m0, 512 * 512, 2 * 512 * 512);
    conv3x3_leaky<17, 9, 8, 64, false><<<dim3(8, 16, 4), 256, 0, stream>>>(
        m0, oW0, oB0, out, nullptr, 512, 512, 17, 2, 17 * 512 * 512, 34 * 512 * 512, 0);

    // level 1 (128^2: 32x32 tiles, OCPT=4 -> 384 blocks)
    conv3x3_leaky<48, 4, 4, 32, false><<<dim3(4, 4, 24), 256, 0, stream>>>(
        x1, iW1, iB1, y1, nullptr, 128, 128, 48, 12, 48 * 128 * 128, 48 * 128 * 128, 0);
    mm_features_kernel<<<(2 * 128 * 128) / 256, 256, 0, stream>>>(y1, m1, 128 * 128, 2 * 128 * 128);
    bicubic_up4_kernel<<<(2 * 17 * 512 * 512) / 256, 256, 0, stream>>>(m1, u, 2 * 17 * 512 * 512);
    conv3x3_leaky<17, 9, 8, 64, false><<<dim3(8, 16, 4), 256, 0, stream>>>(
        u, oW1, oB1, out, nullptr, 512, 512, 17, 2, 17 * 512 * 512, 34 * 512 * 512, 17);
}

// Round 8
// 670.753 us; speedup vs baseline: 2.8537x; 1.0647x over previous
//
#include <hip/hip_runtime.h>
#include <math.h>

// ---------------------------------------------------------------------------
// MuellerMatrixPyramid, fp32, MI355X.
//   conv0 (48->48, 512^2) -> y0 (+fused 4x4 maxpool -> x1, shfl-based)
//   mm0   (y0 -> m0, 17ch)
//   oconv0(m0 -> out[:,0:17])
//   conv1 (48->48, 128^2) -> y1
//   mm1   (y1 -> m1)
//   up    (m1 -> u, bicubic a=-0.75 align_corners, 128->512)
//   oconv1(u -> out[:,17:34])
//
// Conv: R2-proven structure: software-pipelined, double-buffered LDS, ONE
// barrier per channel: load(c+1) regs -> compute(c) from LDS -> ds_write(c+1)
// -> barrier. VGPR ~120, no spill.
//
// HARD-WON RULES (R3-R7 post-mortems):
//  - 128-VGPR CLIFF: hipcc refuses to allocate past 128; excess live set
//    SPILLS acc to scratch (R5/R6: VGPR=128, 5.8 GB/dispatch scratch traffic,
//    4x slowdown). Any schedule change adding >~8 live regs dies.
//    => 2-channels-per-stage pipelining is a DEAD END at this tile size.
//  - s_load weights in the hot loop are POISON: SMEM shares lgkmcnt with DS,
//    returns out-of-order -> full lgkmcnt(0) drains serialize the tile-read
//    pipeline (R3/R4: +50us). Weights stay in LDS; broadcast reads are cheap.
//  - XCD remap of g to fastest blockIdx.x is WRONG (R3: FETCH 233->390MB).
//    g stays in blockIdx.z.
//  - LDS-staged pool epilogue costs more than the maxpool kernel it replaces
//    (R7: +19us for -18us). Pool must be barrier-free => shfl_xor reduction.
//  - SQ_LDS_BANK_CONFLICT ~2.4e7 is intrinsic wave64-b128 service. Ignore.
// ---------------------------------------------------------------------------

__device__ __forceinline__ float leakyf(float t) { return t >= 0.0f ? t : 0.01f * t; }

// 256 threads = XG x-groups * TH rows; each thread PX px * OCPT out-channels.
// grid.z = B * NG.
template<int CIN, int OCPT, int PX, int TW, bool DO_POOL>
__global__ __launch_bounds__(256, 2)
void conv3x3_leaky(const float* __restrict__ in, const float* __restrict__ wgt,
                   const float* __restrict__ bias, float* __restrict__ out,
                   float* __restrict__ pool_out,
                   int H, int W, int COUT, int NG,
                   int in_bstride, int out_bstride, int out_coff)
{
    constexpr int XG     = TW / PX;
    constexpr int TH     = 256 / XG;
    constexpr int COLS   = TW + 2;
    constexpr int ROWS   = TH + 2;
    constexpr int STRIDE = (COLS + 3) & ~3;   // 16B-aligned rows
    constexpr int TSZ    = ROWS * STRIDE;
    constexpr int ELEMS  = ROWS * COLS;
    constexpr int K      = (ELEMS + 255) / 256;
    constexpr int NV     = PX + 2;

    __shared__ float tile[2 * TSZ];           // double buffer
    __shared__ float wlds[CIN * OCPT * 12];   // all weights, staged once
    __shared__ float blds[OCPT];

    const int tid   = threadIdx.x;
    const int tx    = tid & (XG - 1);
    const int ty    = tid / XG;
    const int g     = blockIdx.z % NG;
    const int b     = blockIdx.z / NG;
    const int obase = g * OCPT;
    const int row0  = blockIdx.y * TH;
    const int col0  = blockIdx.x * TW;
    const int HW    = H * W;

    // stage ALL weights once: wlds[c][o][k], k padded to 12
    for (int idx = tid; idx < CIN * OCPT * 9; idx += 256) {
        int c  = idx / (OCPT * 9);
        int r2 = idx - c * (OCPT * 9);
        int o  = r2 / 9;
        int k2 = r2 - o * 9;
        int og = obase + o;
        wlds[(c * OCPT + o) * 12 + k2] = (og < COUT) ? wgt[(og * CIN + c) * 9 + k2] : 0.0f;
    }
    if (tid < OCPT) {
        int og = obase + tid;
        blds[tid] = (og < COUT) ? bias[og] : 0.0f;
    }

    // loop-invariant staging offsets (K regs each)
    int goff[K], loff[K];
#pragma unroll
    for (int k = 0; k < K; ++k) {
        int idx = tid + k * 256;
        if (idx < ELEMS) {
            int r  = idx / COLS;
            int cc = idx - r * COLS;
            int gr = row0 - 1 + r;
            int gc = col0 - 1 + cc;
            bool v = (gr >= 0 && gr < H && gc >= 0 && gc < W);
            goff[k] = v ? (gr * W + gc) : -1;
            loff[k] = r * STRIDE + cc;
        } else {
            goff[k] = -1;
            loff[k] = -1;
        }
    }

    const float* inb = in + b * in_bstride;

    // prologue: stage channel 0 into buffer 0
    float sreg[K];
    {
        const float* ic = inb;   // c = 0
#pragma unroll
        for (int k = 0; k < K; ++k) {
            float v = 0.0f;
            if (goff[k] >= 0) v = ic[goff[k]];
            sreg[k] = v;
        }
#pragma unroll
        for (int k = 0; k < K; ++k)
            if (loff[k] >= 0) tile[loff[k]] = sreg[k];
    }
    __syncthreads();

    float acc[OCPT][PX];
#pragma unroll
    for (int o = 0; o < OCPT; ++o)
#pragma unroll
        for (int p = 0; p < PX; ++p) acc[o][p] = 0.0f;

    for (int c = 0; c < CIN; ++c) {
        // issue next channel's loads (latency overlaps this channel's FMAs)
        if (c + 1 < CIN) {
            const float* ic = inb + (c + 1) * HW;
#pragma unroll
            for (int k = 0; k < K; ++k) {
                float v = 0.0f;
                if (goff[k] >= 0) v = ic[goff[k]];
                sreg[k] = v;
            }
        }

        // compute channel c from buffer (c&1)
        {
            const float* tb = &tile[(c & 1) * TSZ];
            float v[3][NV];
#pragma unroll
            for (int rr = 0; rr < 3; ++rr) {
                const float* tp = tb + (ty + rr) * STRIDE + tx * PX;
                float4 a0 = *(const float4*)tp;
                v[rr][0] = a0.x; v[rr][1] = a0.y; v[rr][2] = a0.z; v[rr][3] = a0.w;
                if constexpr (PX == 8) {
                    float4 a1 = *(const float4*)(tp + 4);
                    float2 a2 = *(const float2*)(tp + 8);
                    v[rr][4] = a1.x; v[rr][5] = a1.y; v[rr][6] = a1.z; v[rr][7] = a1.w;
                    v[rr][8] = a2.x; v[rr][9] = a2.y;
                } else {
                    float2 a1 = *(const float2*)(tp + 4);
                    v[rr][4] = a1.x; v[rr][5] = a1.y;
                }
            }
#pragma unroll
            for (int o = 0; o < OCPT; ++o) {
                const float* wp = &wlds[(c * OCPT + o) * 12];
                float4 w0 = *(const float4*)wp;
                float4 w1 = *(const float4*)(wp + 4);
                float w8 = wp[8];
                float wk[9] = {w0.x, w0.y, w0.z, w0.w, w1.x, w1.y, w1.z, w1.w, w8};
#pragma unroll
                for (int px = 0; px < PX; ++px) {
                    float s = acc[o][px];
#pragma unroll
                    for (int kr = 0; kr < 3; ++kr)
#pragma unroll
                        for (int kc = 0; kc < 3; ++kc)
                            s = fmaf(wk[kr * 3 + kc], v[kr][px + kc], s);
                    acc[o][px] = s;
                }
            }
        }

        // write next channel's tile into the other buffer, then barrier
        if (c + 1 < CIN) {
            float* tb = &tile[((c + 1) & 1) * TSZ];
#pragma unroll
            for (int k = 0; k < K; ++k)
                if (loff[k] >= 0) tb[loff[k]] = sreg[k];
            __syncthreads();   // uniform branch (c uniform) -> legal
        }
    }

    const int orow = row0 + ty;
    float* outb = out + b * out_bstride;
#pragma unroll
    for (int o = 0; o < OCPT; ++o) {
        int og = obase + o;
        if (og < COUT) {
            float bv = blds[o];
            float r[PX];
#pragma unroll
            for (int p = 0; p < PX; ++p) { float t = acc[o][p] + bv; r[p] = leakyf(t); }
            float* op = outb + ((out_coff + og) * H + orow) * W + col0 + tx * PX;
#pragma unroll
            for (int q = 0; q < PX / 4; ++q)
                *(float4*)(op + 4 * q) = make_float4(r[4*q], r[4*q+1], r[4*q+2], r[4*q+3]);
        }
    }

    // ---- fused 4x4 maxpool (conv0 only): shfl_xor reduction, NO barriers ----
    // Thread (ty,tx) holds 8 cols = 2 pool-col groups of its row for each o.
    // The 4 rows of a pool block live at lanes ty^1, ty^2 of the SAME wave
    // (wave = 8 consecutive ty). 2 shfl_xor per value -> row max; lanes with
    // ty%4==0 write 2 pooled floats. Values recomputed as leakyf(acc+bv):
    // bitwise identical to the y0 path; max is order-free.
    if constexpr (DO_POOL) {
        static_assert(PX == 8 && XG == 8, "pool fusion assumes PX=8, XG=8");
        const int pH = H >> 2, pW = W >> 2;
        const int prow = (row0 + ty) >> 2;          // meaningful when ty%4==0
        const int pcol = (col0 >> 2) + tx * 2;
        const bool writer = (ty & 3) == 0;
#pragma unroll
        for (int o = 0; o < OCPT; ++o) {
            float bv = blds[o];
            float c0 = leakyf(acc[o][0] + bv);
            c0 = fmaxf(c0, leakyf(acc[o][1] + bv));
            c0 = fmaxf(c0, leakyf(acc[o][2] + bv));
            c0 = fmaxf(c0, leakyf(acc[o][3] + bv));
            float c1 = leakyf(acc[o][4] + bv);
            c1 = fmaxf(c1, leakyf(acc[o][5] + bv));
            c1 = fmaxf(c1, leakyf(acc[o][6] + bv));
            c1 = fmaxf(c1, leakyf(acc[o][7] + bv));
            c0 = fmaxf(c0, __shfl_xor(c0, 8));
            c0 = fmaxf(c0, __shfl_xor(c0, 16));
            c1 = fmaxf(c1, __shfl_xor(c1, 8));
            c1 = fmaxf(c1, __shfl_xor(c1, 16));
            if (writer) {
                int og = obase + o;
                *(float2*)(pool_out + ((size_t)(b * COUT + og) * pH + prow) * pW + pcol)
                    = make_float2(c0, c1);
            }
        }
    }
}

// ---------------- 4x4 inverse (double, adjugate) ---------------------------
__device__ __forceinline__ void inv4x4(const double* m, double* invOut)
{
    double inv[16];
    inv[0]  =  m[5]*m[10]*m[15] - m[5]*m[11]*m[14] - m[9]*m[6]*m[15] + m[9]*m[7]*m[14] + m[13]*m[6]*m[11] - m[13]*m[7]*m[10];
    inv[4]  = -m[4]*m[10]*m[15] + m[4]*m[11]*m[14] + m[8]*m[6]*m[15] - m[8]*m[7]*m[14] - m[12]*m[6]*m[11] + m[12]*m[7]*m[10];
    inv[8]  =  m[4]*m[9]*m[15]  - m[4]*m[11]*m[13] - m[8]*m[5]*m[15] + m[8]*m[7]*m[13] + m[12]*m[5]*m[11] - m[12]*m[7]*m[9];
    inv[12] = -m[4]*m[9]*m[14]  + m[4]*m[10]*m[13] + m[8]*m[5]*m[14] - m[8]*m[6]*m[13] - m[12]*m[5]*m[10] + m[12]*m[6]*m[9];
    inv[1]  = -m[1]*m[10]*m[15] + m[1]*m[11]*m[14] + m[9]*m[2]*m[15] - m[9]*m[3]*m[14] - m[13]*m[2]*m[11] + m[13]*m[3]*m[10];
    inv[5]  =  m[0]*m[10]*m[15] - m[0]*m[11]*m[14] - m[8]*m[2]*m[15] + m[8]*m[3]*m[14] + m[12]*m[2]*m[11] - m[12]*m[3]*m[10];
    inv[9]  = -m[0]*m[9]*m[15]  + m[0]*m[11]*m[13] + m[8]*m[1]*m[15] - m[8]*m[3]*m[13] - m[12]*m[1]*m[11] + m[12]*m[3]*m[9];
    inv[13] =  m[0]*m[9]*m[14]  - m[0]*m[10]*m[13] - m[8]*m[1]*m[14] + m[8]*m[2]*m[13] + m[12]*m[1]*m[10] - m[12]*m[2]*m[9];
    inv[2]  =  m[1]*m[6]*m[15]  - m[1]*m[7]*m[14]  - m[5]*m[2]*m[15] + m[5]*m[3]*m[14] + m[13]*m[2]*m[7]  - m[13]*m[3]*m[6];
    inv[6]  = -m[0]*m[6]*m[15]  + m[0]*m[7]*m[14]  + m[4]*m[2]*m[15] - m[4]*m[3]*m[14] - m[12]*m[2]*m[7]  + m[12]*m[3]*m[6];
    inv[10] =  m[0]*m[5]*m[15]  - m[0]*m[7]*m[13]  - m[4]*m[1]*m[15] + m[4]*m[3]*m[13] + m[12]*m[1]*m[7]  - m[12]*m[3]*m[5];
    inv[14] = -m[0]*m[5]*m[14]  + m[0]*m[6]*m[13]  + m[4]*m[1]*m[14] - m[4]*m[2]*m[13] - m[12]*m[1]*m[6]  + m[12]*m[2]*m[5];
    inv[3]  = -m[1]*m[6]*m[11]  + m[1]*m[7]*m[10]  + m[5]*m[2]*m[11] - m[5]*m[3]*m[10] - m[9]*m[2]*m[7]   + m[9]*m[3]*m[6];
    inv[7]  =  m[0]*m[6]*m[11]  - m[0]*m[7]*m[10]  - m[4]*m[2]*m[11] + m[4]*m[3]*m[10] + m[8]*m[2]*m[7]   - m[8]*m[3]*m[6];
    inv[11] = -m[0]*m[5]*m[11]  + m[0]*m[7]*m[9]   + m[4]*m[1]*m[11] - m[4]*m[3]*m[9]  - m[8]*m[1]*m[7]   + m[8]*m[3]*m[5];
    inv[15] =  m[0]*m[5]*m[10]  - m[0]*m[6]*m[9]   - m[4]*m[1]*m[10] + m[4]*m[2]*m[9]  + m[8]*m[1]*m[6]   - m[8]*m[2]*m[5];
    double det = m[0]*inv[0] + m[1]*inv[4] + m[2]*inv[8] + m[3]*inv[12];
    det = 1.0 / det;
#pragma unroll
    for (int i = 0; i < 16; ++i) invOut[i] = inv[i] * det;
}

__device__ __forceinline__ void matmul4(const double* A, const double* B, double* C)
{
#pragma unroll
    for (int r = 0; r < 4; ++r)
#pragma unroll
        for (int c = 0; c < 4; ++c) {
            double s = 0.0;
#pragma unroll
            for (int k = 0; k < 4; ++k) s += A[r * 4 + k] * B[k * 4 + c];
            C[r * 4 + c] = s;
        }
}

// ---------------- mm_features: (b,48,h,w) -> (b,17,h,w) --------------------
__global__ __launch_bounds__(256)
void mm_features_kernel(const float* __restrict__ y, float* __restrict__ m, int HW, int n)
{
    int p = blockIdx.x * 256 + threadIdx.x;
    if (p >= n) return;
    int b  = p / HW;
    int sp = p - b * HW;
    const float* base = y + (size_t)b * 48 * HW + sp;

    double A[16];
#pragma unroll
    for (int i = 0; i < 16; ++i) {
        double e = (i == 0 || i == 5 || i == 10 || i == 15) ? 1e-4 : 0.0;
        A[i] = (double)base[(16 + i) * HW] + e;
    }
    double iA[16];
    inv4x4(A, iA);                     // A dead

    double F[16];
    double s = 0.0;
#pragma unroll
    for (int i = 0; i < 16; ++i) { F[i] = (double)base[i * HW]; }
#pragma unroll
    for (int i = 0; i < 16; ++i) s += F[i];
    s *= (1.0 / 16.0);

    double T[16];
    matmul4(iA, F, T);                 // iA, F dead

    double Wm[16];
#pragma unroll
    for (int i = 0; i < 16; ++i) {
        double e = (i == 0 || i == 5 || i == 10 || i == 15) ? 1e-4 : 0.0;
        Wm[i] = (double)base[(32 + i) * HW] + e;
    }
    double iW[16];
    inv4x4(Wm, iW);                    // Wm dead

    double M[16];
    matmul4(T, iW, M);

    float* ob = m + (size_t)b * 17 * HW + sp;
    ob[0] = (float)s;
#pragma unroll
    for (int i = 0; i < 16; ++i) ob[(1 + i) * HW] = (float)M[i];
}

// ---------------- bicubic x4 upsample 128->512, align_corners, a=-0.75 -----
__device__ __forceinline__ double cubw(double t)
{
    const double a = -0.75;
    t = fabs(t);
    if (t <= 1.0) return ((a + 2.0) * t - (a + 3.0)) * t * t + 1.0;
    if (t < 2.0)  return (((t - 5.0) * t + 8.0) * t - 4.0) * a;
    return 0.0;
}

__global__ __launch_bounds__(256)
void bicubic_up4_kernel(const float* __restrict__ src, float* __restrict__ dst, int n)
{
    int idx = blockIdx.x * 256 + threadIdx.x;
    if (idx >= n) return;
    int P  = idx & 511;
    int O  = (idx >> 9) & 511;
    int bc = idx >> 18;                 // b*17 + c
    const double scale = 127.0 / 511.0;
    double sh = O * scale, sw = P * scale;
    int i0 = (int)floor(sh), j0 = (int)floor(sw);
    double wh[4], ww[4];
#pragma unroll
    for (int k = 0; k < 4; ++k) {
        wh[k] = cubw(sh - (double)(i0 + k - 1));
        ww[k] = cubw(sw - (double)(j0 + k - 1));
    }
    const float* sp = src + bc * 16384;
    double acc = 0.0;
#pragma unroll
    for (int ki = 0; ki < 4; ++ki) {
        int ih = min(max(i0 - 1 + ki, 0), 127);
        double rs = 0.0;
#pragma unroll
        for (int kj = 0; kj < 4; ++kj) {
            int iw = min(max(j0 - 1 + kj, 0), 127);
            rs += ww[kj] * (double)sp[ih * 128 + iw];
        }
        acc += wh[ki] * rs;
    }
    dst[idx] = (float)acc;
}

// ---------------------------------------------------------------------------
extern "C" void kernel_launch(void* const* d_in, const int* in_sizes, int n_in,
                              void* d_out, int out_size, void* d_ws, size_t ws_size,
                              hipStream_t stream)
{
    const float* x   = (const float*)d_in[0];
    const float* iW0 = (const float*)d_in[1];
    const float* iB0 = (const float*)d_in[2];
    const float* iW1 = (const float*)d_in[3];
    const float* iB1 = (const float*)d_in[4];
    const float* oW0 = (const float*)d_in[5];
    const float* oB0 = (const float*)d_in[6];
    const float* oW1 = (const float*)d_in[7];
    const float* oB1 = (const float*)d_in[8];
    float* out = (float*)d_out;
    float* ws  = (float*)d_ws;

    // workspace layout (floats)
    float* y0 = ws;                     //  2*48*512*512 = 25165824
    float* m0 = ws + 25165824;          //  2*17*512*512 =  8912896
    float* x1 = ws + 34078720;          //  2*48*128*128 =  1572864
    float* y1 = ws + 35651584;          //  1572864
    float* m1 = ws + 37224448;          //  2*17*128*128 =   557056
    float* u  = ws;                     //  reuse y0 region (y0 dead by then)

    // level 0 (maxpool fused into conv0 epilogue via shfl -> x1)
    conv3x3_leaky<48, 8, 8, 64, true><<<dim3(8, 16, 12), 256, 0, stream>>>(
        x, iW0, iB0, y0, x1, 512, 512, 48, 6, 48 * 512 * 512, 48 * 512 * 512, 0);
    mm_features_kernel<<<(2 * 512 * 512) / 256, 256, 0, stream>>>(y0, m0, 512 * 512, 2 * 512 * 512);
    conv3x3_leaky<17, 9, 8, 64, false><<<dim3(8, 16, 4), 256, 0, stream>>>(
        m0, oW0, oB0, out, nullptr, 512, 512, 17, 2, 17 * 512 * 512, 34 * 512 * 512, 0);

    // level 1 (128^2: 32x32 tiles, OCPT=4 -> 384 blocks)
    conv3x3_leaky<48, 4, 4, 32, false><<<dim3(4, 4, 24), 256, 0, stream>>>(
        x1, iW1, iB1, y1, nullptr, 128, 128, 48, 12, 48 * 128 * 128, 48 * 128 * 128, 0);
    mm_features_kernel<<<(2 * 128 * 128) / 256, 256, 0, stream>>>(y1, m1, 128 * 128, 2 * 128 * 128);
    bicubic_up4_kernel<<<(2 * 17 * 512 * 512) / 256, 256, 0, stream>>>(m1, u, 2 * 17 * 512 * 512);
    conv3x3_leaky<17, 9, 8, 64, false><<<dim3(8, 16, 4), 256, 0, stream>>>(
        u, oW1, oB1, out, nullptr, 512, 512, 17, 2, 17 * 512 * 512, 34 * 512 * 512, 17);
}

// Round 9
// 632.531 us; speedup vs baseline: 3.0262x; 1.0604x over previous
//
#include <hip/hip_runtime.h>
#include <math.h>

// ---------------------------------------------------------------------------
// MuellerMatrixPyramid, fp32, MI355X.  5-dispatch DAG (R9):
//   conv0 (48->48, 512^2) -> y0 (+fused shfl 4x4 maxpool -> x1)
//   conv1 (48->48, 128^2) -> y1
//   mm_both: y0 -> m0 (512^2) AND y1 -> m1 (128^2), one dispatch
//   up    (m1 -> u, bicubic a=-0.75 align_corners f32, 128->512)
//   oconv_both: oconv0(m0 -> out[:,0:17]) AND oconv1(u -> out[:,17:34]),
//               one dispatch (z-split pointer select, block-uniform)
//
// Conv: R2-proven structure: software-pipelined, double-buffered LDS, ONE
// barrier per channel: load(c+1) regs -> compute(c) from LDS -> ds_write(c+1)
// -> barrier. VGPR ~124, no spill.
//
// HARD-WON RULES (R3-R8 post-mortems):
//  - 128-VGPR CLIFF: hipcc refuses to allocate past 128; excess live set
//    SPILLS acc to scratch (R5/R6: VGPR=128, 5.8 GB/dispatch scratch traffic,
//    4x slowdown). Any schedule change adding >~8 live regs dies.
//    => 2-channels-per-stage pipelining is a DEAD END at this tile size.
//  - s_load weights in the hot loop are POISON: SMEM shares lgkmcnt with DS,
//    returns out-of-order -> full lgkmcnt(0) drains serialize the tile-read
//    pipeline (R3/R4: +50us). Weights stay in LDS; broadcast reads are cheap.
//  - XCD remap of g to fastest blockIdx.x is WRONG (R3: FETCH 233->390MB).
//    g stays slowest (within z).
//  - LDS-staged pool epilogue costs more than the kernel it replaces (R7:
//    +19us). Barrier-free shfl_xor pool epilogue is free (R8: +0us).
//  - mm stays DOUBLE: near-singular pixels (absmax 8.5e5 => cond ~1e4)
//    amplify inverse rounding; don't gamble.
//  - SQ_LDS_BANK_CONFLICT ~2.3e7 is intrinsic wave64-b128 service. Ignore.
// ---------------------------------------------------------------------------

__device__ __forceinline__ float leakyf(float t) { return t >= 0.0f ? t : 0.01f * t; }

// 256 threads = XG x-groups * TH rows; each thread PX px * OCPT out-channels.
// grid.z = B * NG  (TWO_SRC: plus second instance above z_split).
template<int CIN, int OCPT, int PX, int TW, bool DO_POOL, bool TWO_SRC>
__global__ __launch_bounds__(256, 2)
void conv3x3_leaky(const float* __restrict__ in, const float* __restrict__ wgt,
                   const float* __restrict__ bias, float* __restrict__ out,
                   float* __restrict__ pool_out,
                   int H, int W, int COUT, int NG,
                   int in_bstride, int out_bstride, int out_coff,
                   const float* __restrict__ in2, const float* __restrict__ wgt2,
                   const float* __restrict__ bias2, int coff2, int z_split)
{
    constexpr int XG     = TW / PX;
    constexpr int TH     = 256 / XG;
    constexpr int COLS   = TW + 2;
    constexpr int ROWS   = TH + 2;
    constexpr int STRIDE = (COLS + 3) & ~3;   // 16B-aligned rows
    constexpr int TSZ    = ROWS * STRIDE;
    constexpr int ELEMS  = ROWS * COLS;
    constexpr int K      = (ELEMS + 255) / 256;
    constexpr int NV     = PX + 2;

    __shared__ float tile[2 * TSZ];           // double buffer
    __shared__ float wlds[CIN * OCPT * 12];   // all weights, staged once
    __shared__ float blds[OCPT];

    // instance select (block-uniform; folds away when !TWO_SRC)
    const float* insel = in;
    const float* wsel  = wgt;
    const float* bsel  = bias;
    int coff = out_coff;
    int bz   = blockIdx.z;
    if (TWO_SRC && bz >= z_split) {
        bz -= z_split;
        insel = in2; wsel = wgt2; bsel = bias2; coff = coff2;
    }

    const int tid   = threadIdx.x;
    const int tx    = tid & (XG - 1);
    const int ty    = tid / XG;
    const int g     = bz % NG;
    const int b     = bz / NG;
    const int obase = g * OCPT;
    const int row0  = blockIdx.y * TH;
    const int col0  = blockIdx.x * TW;
    const int HW    = H * W;

    // stage ALL weights once: wlds[c][o][k], k padded to 12
    for (int idx = tid; idx < CIN * OCPT * 9; idx += 256) {
        int c  = idx / (OCPT * 9);
        int r2 = idx - c * (OCPT * 9);
        int o  = r2 / 9;
        int k2 = r2 - o * 9;
        int og = obase + o;
        wlds[(c * OCPT + o) * 12 + k2] = (og < COUT) ? wsel[(og * CIN + c) * 9 + k2] : 0.0f;
    }
    if (tid < OCPT) {
        int og = obase + tid;
        blds[tid] = (og < COUT) ? bsel[og] : 0.0f;
    }

    // loop-invariant staging offsets (K regs each)
    int goff[K], loff[K];
#pragma unroll
    for (int k = 0; k < K; ++k) {
        int idx = tid + k * 256;
        if (idx < ELEMS) {
            int r  = idx / COLS;
            int cc = idx - r * COLS;
            int gr = row0 - 1 + r;
            int gc = col0 - 1 + cc;
            bool v = (gr >= 0 && gr < H && gc >= 0 && gc < W);
            goff[k] = v ? (gr * W + gc) : -1;
            loff[k] = r * STRIDE + cc;
        } else {
            goff[k] = -1;
            loff[k] = -1;
        }
    }

    const float* inb = insel + (size_t)b * in_bstride;

    // prologue: stage channel 0 into buffer 0
    float sreg[K];
    {
        const float* ic = inb;   // c = 0
#pragma unroll
        for (int k = 0; k < K; ++k) {
            float v = 0.0f;
            if (goff[k] >= 0) v = ic[goff[k]];
            sreg[k] = v;
        }
#pragma unroll
        for (int k = 0; k < K; ++k)
            if (loff[k] >= 0) tile[loff[k]] = sreg[k];
    }
    __syncthreads();

    float acc[OCPT][PX];
#pragma unroll
    for (int o = 0; o < OCPT; ++o)
#pragma unroll
        for (int p = 0; p < PX; ++p) acc[o][p] = 0.0f;

    for (int c = 0; c < CIN; ++c) {
        // issue next channel's loads (latency overlaps this channel's FMAs)
        if (c + 1 < CIN) {
            const float* ic = inb + (c + 1) * HW;
#pragma unroll
            for (int k = 0; k < K; ++k) {
                float v = 0.0f;
                if (goff[k] >= 0) v = ic[goff[k]];
                sreg[k] = v;
            }
        }

        // compute channel c from buffer (c&1)
        {
            const float* tb = &tile[(c & 1) * TSZ];
            float v[3][NV];
#pragma unroll
            for (int rr = 0; rr < 3; ++rr) {
                const float* tp = tb + (ty + rr) * STRIDE + tx * PX;
                float4 a0 = *(const float4*)tp;
                v[rr][0] = a0.x; v[rr][1] = a0.y; v[rr][2] = a0.z; v[rr][3] = a0.w;
                if constexpr (PX == 8) {
                    float4 a1 = *(const float4*)(tp + 4);
                    float2 a2 = *(const float2*)(tp + 8);
                    v[rr][4] = a1.x; v[rr][5] = a1.y; v[rr][6] = a1.z; v[rr][7] = a1.w;
                    v[rr][8] = a2.x; v[rr][9] = a2.y;
                } else {
                    float2 a1 = *(const float2*)(tp + 4);
                    v[rr][4] = a1.x; v[rr][5] = a1.y;
                }
            }
#pragma unroll
            for (int o = 0; o < OCPT; ++o) {
                const float* wp = &wlds[(c * OCPT + o) * 12];
                float4 w0 = *(const float4*)wp;
                float4 w1 = *(const float4*)(wp + 4);
                float w8 = wp[8];
                float wk[9] = {w0.x, w0.y, w0.z, w0.w, w1.x, w1.y, w1.z, w1.w, w8};
#pragma unroll
                for (int px = 0; px < PX; ++px) {
                    float s = acc[o][px];
#pragma unroll
                    for (int kr = 0; kr < 3; ++kr)
#pragma unroll
                        for (int kc = 0; kc < 3; ++kc)
                            s = fmaf(wk[kr * 3 + kc], v[kr][px + kc], s);
                    acc[o][px] = s;
                }
            }
        }

        // write next channel's tile into the other buffer, then barrier
        if (c + 1 < CIN) {
            float* tb = &tile[((c + 1) & 1) * TSZ];
#pragma unroll
            for (int k = 0; k < K; ++k)
                if (loff[k] >= 0) tb[loff[k]] = sreg[k];
            __syncthreads();   // uniform branch (c uniform) -> legal
        }
    }

    const int orow = row0 + ty;
    float* outb = out + (size_t)b * out_bstride;
#pragma unroll
    for (int o = 0; o < OCPT; ++o) {
        int og = obase + o;
        if (og < COUT) {
            float bv = blds[o];
            float r[PX];
#pragma unroll
            for (int p = 0; p < PX; ++p) { float t = acc[o][p] + bv; r[p] = leakyf(t); }
            float* op = outb + ((coff + og) * H + orow) * W + col0 + tx * PX;
#pragma unroll
            for (int q = 0; q < PX / 4; ++q)
                *(float4*)(op + 4 * q) = make_float4(r[4*q], r[4*q+1], r[4*q+2], r[4*q+3]);
        }
    }

    // ---- fused 4x4 maxpool (conv0 only): shfl_xor reduction, NO barriers ----
    if constexpr (DO_POOL) {
        static_assert(PX == 8 && XG == 8, "pool fusion assumes PX=8, XG=8");
        const int pH = H >> 2, pW = W >> 2;
        const int prow = (row0 + ty) >> 2;          // meaningful when ty%4==0
        const int pcol = (col0 >> 2) + tx * 2;
        const bool writer = (ty & 3) == 0;
#pragma unroll
        for (int o = 0; o < OCPT; ++o) {
            float bv = blds[o];
            float c0 = leakyf(acc[o][0] + bv);
            c0 = fmaxf(c0, leakyf(acc[o][1] + bv));
            c0 = fmaxf(c0, leakyf(acc[o][2] + bv));
            c0 = fmaxf(c0, leakyf(acc[o][3] + bv));
            float c1 = leakyf(acc[o][4] + bv);
            c1 = fmaxf(c1, leakyf(acc[o][5] + bv));
            c1 = fmaxf(c1, leakyf(acc[o][6] + bv));
            c1 = fmaxf(c1, leakyf(acc[o][7] + bv));
            c0 = fmaxf(c0, __shfl_xor(c0, 8));
            c0 = fmaxf(c0, __shfl_xor(c0, 16));
            c1 = fmaxf(c1, __shfl_xor(c1, 8));
            c1 = fmaxf(c1, __shfl_xor(c1, 16));
            if (writer) {
                int og = obase + o;
                *(float2*)(pool_out + ((size_t)(b * COUT + og) * pH + prow) * pW + pcol)
                    = make_float2(c0, c1);
            }
        }
    }
}

// ---------------- 4x4 inverse (double, adjugate) ---------------------------
__device__ __forceinline__ void inv4x4(const double* m, double* invOut)
{
    double inv[16];
    inv[0]  =  m[5]*m[10]*m[15] - m[5]*m[11]*m[14] - m[9]*m[6]*m[15] + m[9]*m[7]*m[14] + m[13]*m[6]*m[11] - m[13]*m[7]*m[10];
    inv[4]  = -m[4]*m[10]*m[15] + m[4]*m[11]*m[14] + m[8]*m[6]*m[15] - m[8]*m[7]*m[14] - m[12]*m[6]*m[11] + m[12]*m[7]*m[10];
    inv[8]  =  m[4]*m[9]*m[15]  - m[4]*m[11]*m[13] - m[8]*m[5]*m[15] + m[8]*m[7]*m[13] + m[12]*m[5]*m[11] - m[12]*m[7]*m[9];
    inv[12] = -m[4]*m[9]*m[14]  + m[4]*m[10]*m[13] + m[8]*m[5]*m[14] - m[8]*m[6]*m[13] - m[12]*m[5]*m[10] + m[12]*m[6]*m[9];
    inv[1]  = -m[1]*m[10]*m[15] + m[1]*m[11]*m[14] + m[9]*m[2]*m[15] - m[9]*m[3]*m[14] - m[13]*m[2]*m[11] + m[13]*m[3]*m[10];
    inv[5]  =  m[0]*m[10]*m[15] - m[0]*m[11]*m[14] - m[8]*m[2]*m[15] + m[8]*m[3]*m[14] + m[12]*m[2]*m[11] - m[12]*m[3]*m[10];
    inv[9]  = -m[0]*m[9]*m[15]  + m[0]*m[11]*m[13] + m[8]*m[1]*m[15] - m[8]*m[3]*m[13] - m[12]*m[1]*m[11] + m[12]*m[3]*m[9];
    inv[13] =  m[0]*m[9]*m[14]  - m[0]*m[10]*m[13] - m[8]*m[1]*m[14] + m[8]*m[2]*m[13] + m[12]*m[1]*m[10] - m[12]*m[2]*m[9];
    inv[2]  =  m[1]*m[6]*m[15]  - m[1]*m[7]*m[14]  - m[5]*m[2]*m[15] + m[5]*m[3]*m[14] + m[13]*m[2]*m[7]  - m[13]*m[3]*m[6];
    inv[6]  = -m[0]*m[6]*m[15]  + m[0]*m[7]*m[14]  + m[4]*m[2]*m[15] - m[4]*m[3]*m[14] - m[12]*m[2]*m[7]  + m[12]*m[3]*m[6];
    inv[10] =  m[0]*m[5]*m[15]  - m[0]*m[7]*m[13]  - m[4]*m[1]*m[15] + m[4]*m[3]*m[13] + m[12]*m[1]*m[7]  - m[12]*m[3]*m[5];
    inv[14] = -m[0]*m[5]*m[14]  + m[0]*m[6]*m[13]  + m[4]*m[1]*m[14] - m[4]*m[2]*m[13] - m[12]*m[1]*m[6]  + m[12]*m[2]*m[5];
    inv[3]  = -m[1]*m[6]*m[11]  + m[1]*m[7]*m[10]  + m[5]*m[2]*m[11] - m[5]*m[3]*m[10] - m[9]*m[2]*m[7]   + m[9]*m[3]*m[6];
    inv[7]  =  m[0]*m[6]*m[11]  - m[0]*m[7]*m[10]  - m[4]*m[2]*m[11] + m[4]*m[3]*m[10] + m[8]*m[2]*m[7]   - m[8]*m[3]*m[6];
    inv[11] = -m[0]*m[5]*m[11]  + m[0]*m[7]*m[9]   + m[4]*m[1]*m[11] - m[4]*m[3]*m[9]  - m[8]*m[1]*m[7]   + m[8]*m[3]*m[5];
    inv[15] =  m[0]*m[5]*m[10]  - m[0]*m[6]*m[9]   - m[4]*m[1]*m[10] + m[4]*m[2]*m[9]  + m[8]*m[1]*m[6]   - m[8]*m[2]*m[5];
    double det = m[0]*inv[0] + m[1]*inv[4] + m[2]*inv[8] + m[3]*inv[12];
    det = 1.0 / det;
#pragma unroll
    for (int i = 0; i < 16; ++i) invOut[i] = inv[i] * det;
}

__device__ __forceinline__ void matmul4(const double* A, const double* B, double* C)
{
#pragma unroll
    for (int r = 0; r < 4; ++r)
#pragma unroll
        for (int c = 0; c < 4; ++c) {
            double s = 0.0;
#pragma unroll
            for (int k = 0; k < 4; ++k) s += A[r * 4 + k] * B[k * 4 + c];
            C[r * 4 + c] = s;
        }
}

// ---------------- mm_features, both pyramid levels in one dispatch ---------
__global__ __launch_bounds__(256)
void mm_features_kernel(const float* __restrict__ y0, float* __restrict__ m0,
                        int HW0, int n0,
                        const float* __restrict__ y1, float* __restrict__ m1,
                        int HW1, int ntot)
{
    int p = blockIdx.x * 256 + threadIdx.x;
    if (p >= ntot) return;
    const float* y; float* mo; int HW;
    if (p < n0) { y = y0; mo = m0; HW = HW0; }
    else        { p -= n0; y = y1; mo = m1; HW = HW1; }
    int b  = p / HW;
    int sp = p - b * HW;
    const float* base = y + (size_t)b * 48 * HW + sp;

    double A[16];
#pragma unroll
    for (int i = 0; i < 16; ++i) {
        double e = (i == 0 || i == 5 || i == 10 || i == 15) ? 1e-4 : 0.0;
        A[i] = (double)base[(16 + i) * HW] + e;
    }
    double iA[16];
    inv4x4(A, iA);                     // A dead

    double F[16];
    double s = 0.0;
#pragma unroll
    for (int i = 0; i < 16; ++i) { F[i] = (double)base[i * HW]; }
#pragma unroll
    for (int i = 0; i < 16; ++i) s += F[i];
    s *= (1.0 / 16.0);

    double T[16];
    matmul4(iA, F, T);                 // iA, F dead

    double Wm[16];
#pragma unroll
    for (int i = 0; i < 16; ++i) {
        double e = (i == 0 || i == 5 || i == 10 || i == 15) ? 1e-4 : 0.0;
        Wm[i] = (double)base[(32 + i) * HW] + e;
    }
    double iW[16];
    inv4x4(Wm, iW);                    // Wm dead

    double M[16];
    matmul4(T, iW, M);

    float* ob = mo + (size_t)b * 17 * HW + sp;
    ob[0] = (float)s;
#pragma unroll
    for (int i = 0; i < 16; ++i) ob[(1 + i) * HW] = (float)M[i];
}

// ---------------- bicubic x4 upsample 128->512, align_corners, a=-0.75 -----
// f32 path (R9): reference is f32 end-to-end (JAX default); weight function is
// continuous across the floor boundary, so f32 src/weights shift results by
// ~1e-5 relative -- same order as ref's own f32 einsum rounding.
__device__ __forceinline__ float cubwf(float t)
{
    t = fabsf(t);
    if (t <= 1.0f) return (1.25f * t - 2.25f) * t * t + 1.0f;          // a=-0.75
    if (t < 2.0f)  return (((t - 5.0f) * t + 8.0f) * t - 4.0f) * -0.75f;
    return 0.0f;
}

__global__ __launch_bounds__(256)
void bicubic_up4_kernel(const float* __restrict__ src, float* __restrict__ dst, int n)
{
    int idx = blockIdx.x * 256 + threadIdx.x;
    if (idx >= n) return;
    int P  = idx & 511;
    int O  = (idx >> 9) & 511;
    int bc = idx >> 18;                 // b*17 + c
    const float scale = 127.0f / 511.0f;
    float sh = O * scale, sw = P * scale;
    int i0 = (int)floorf(sh), j0 = (int)floorf(sw);
    float wh[4], ww[4];
#pragma unroll
    for (int k = 0; k < 4; ++k) {
        wh[k] = cubwf(sh - (float)(i0 + k - 1));
        ww[k] = cubwf(sw - (float)(j0 + k - 1));
    }
    const float* sp = src + bc * 16384;
    float acc = 0.0f;
#pragma unroll
    for (int ki = 0; ki < 4; ++ki) {
        int ih = min(max(i0 - 1 + ki, 0), 127);
        float rs = 0.0f;
#pragma unroll
        for (int kj = 0; kj < 4; ++kj) {
            int iw = min(max(j0 - 1 + kj, 0), 127);
            rs = fmaf(ww[kj], sp[ih * 128 + iw], rs);
        }
        acc = fmaf(wh[ki], rs, acc);
    }
    dst[idx] = acc;
}

// ---------------------------------------------------------------------------
extern "C" void kernel_launch(void* const* d_in, const int* in_sizes, int n_in,
                              void* d_out, int out_size, void* d_ws, size_t ws_size,
                              hipStream_t stream)
{
    const float* x   = (const float*)d_in[0];
    const float* iW0 = (const float*)d_in[1];
    const float* iB0 = (const float*)d_in[2];
    const float* iW1 = (const float*)d_in[3];
    const float* iB1 = (const float*)d_in[4];
    const float* oW0 = (const float*)d_in[5];
    const float* oB0 = (const float*)d_in[6];
    const float* oW1 = (const float*)d_in[7];
    const float* oB1 = (const float*)d_in[8];
    float* out = (float*)d_out;
    float* ws  = (float*)d_ws;

    // workspace layout (floats)
    float* y0 = ws;                     //  2*48*512*512 = 25165824
    float* m0 = ws + 25165824;          //  2*17*512*512 =  8912896
    float* x1 = ws + 34078720;          //  2*48*128*128 =  1572864
    float* y1 = ws + 35651584;          //  1572864
    float* m1 = ws + 37224448;          //  2*17*128*128 =   557056
    float* u  = ws;                     //  reuse y0 region (y0 dead by then)

    // conv0 (maxpool fused via shfl -> x1)
    conv3x3_leaky<48, 8, 8, 64, true, false><<<dim3(8, 16, 12), 256, 0, stream>>>(
        x, iW0, iB0, y0, x1, 512, 512, 48, 6, 48 * 512 * 512, 48 * 512 * 512, 0,
        nullptr, nullptr, nullptr, 0, 0);

    // conv1 (128^2: 32x32 tiles, OCPT=4 -> 384 blocks)
    conv3x3_leaky<48, 4, 4, 32, false, false><<<dim3(4, 4, 24), 256, 0, stream>>>(
        x1, iW1, iB1, y1, nullptr, 128, 128, 48, 12, 48 * 128 * 128, 48 * 128 * 128, 0,
        nullptr, nullptr, nullptr, 0, 0);

    // mm for both levels: n0 = 2*512^2 (divisible by 256 -> block-uniform split)
    mm_features_kernel<<<(2 * 512 * 512 + 2 * 128 * 128) / 256, 256, 0, stream>>>(
        y0, m0, 512 * 512, 2 * 512 * 512, y1, m1, 128 * 128,
        2 * 512 * 512 + 2 * 128 * 128);

    // bicubic upsample (f32)
    bicubic_up4_kernel<<<(2 * 17 * 512 * 512) / 256, 256, 0, stream>>>(m1, u, 2 * 17 * 512 * 512);

    // oconv0 + oconv1 merged: z<4 -> (m0,oW0,oB0,coff 0); z>=4 -> (u,oW1,oB1,coff 17)
    conv3x3_leaky<17, 9, 8, 64, false, true><<<dim3(8, 16, 8), 256, 0, stream>>>(
        m0, oW0, oB0, out, nullptr, 512, 512, 17, 2, 17 * 512 * 512, 34 * 512 * 512, 0,
        u, oW1, oB1, 17, 4);
}